// Round 18
// baseline (85.103 us; speedup 1.0000x reference)
//
#include <hip/hip_runtime.h>

#define SEQ 79
#define DM 1024
#define BATCHN 512
#define NROWS (BATCHN * SEQ)        // 40448
#define NPB (SEQ * SEQ)             // 6241
#define P 36                        // k-pitch in floats
#define VOFF (SEQ * P)              // 2844
#define COFF (2 * SEQ * P)          // 5688
#define WS_PER_B 5776               // 23.1 KB per batch in ws

typedef float v2f   __attribute__((ext_vector_type(2)));
typedef float f32x4 __attribute__((ext_vector_type(4)));
typedef short short8 __attribute__((ext_vector_type(8)));

__device__ __forceinline__ unsigned cvt_pk_bf16(float lo, float hi) {
    unsigned r;
    asm("v_cvt_pk_bf16_f32 %0, %1, %2" : "=v"(r) : "v"(lo), "v"(hi));
    return r;
}

// DPP lane-shuffle add on the VALU pipe (not LDS): 0xB1=xor1, 0x4E=xor2,
// 0x124=row_ror:4, 0x128=row_ror:8 -> 16-lane sums after 4 steps.
template <int CTRL>
__device__ __forceinline__ float dpp_add(float v) {
    int t = __builtin_amdgcn_update_dpp(0, __builtin_bit_cast(int, v),
                                        CTRL, 0xf, 0xf, false);
    return v + __builtin_bit_cast(float, t);
}

__device__ __forceinline__ v2f gelu2(v2f a) {
    // gelu(a) = a - a / (exp2(c1*a + c2*a^3) + 1)
    const v2f C1 = {2.3022585093f, 2.3022585093f};
    const v2f C2 = {0.1029450750f, 0.1029450750f};
    v2f tt = a * (a * a * C2 + C1);
    v2f e;
    e.x = __builtin_amdgcn_exp2f(tt.x);
    e.y = __builtin_amdgcn_exp2f(tt.y);
    v2f ep = e + (v2f){1.f, 1.f};
    v2f r;
    r.x = __builtin_amdgcn_rcpf(ep.x);
    r.y = __builtin_amdgcn_rcpf(ep.y);
    return a - a * r;
}

// ---------------- K1: per-(b,n) row -> ws (u/v/col, P=36 layout) ----------
// R7's proven k1 + R16's DPP reduce. One wave per row, grid-stride.
__global__ __launch_bounds__(256) void k1_embed(
    const float* __restrict__ x,
    const float* __restrict__ piece_w, const float* __restrict__ piece_b,
    const float* __restrict__ color_w, const float* __restrict__ color_b,
    const float* __restrict__ mlp1_w,  const float* __restrict__ mlp1_b,
    float* __restrict__ ws)
{
    const int lane = threadIdx.x & 63;
    const int wid  = (blockIdx.x * blockDim.x + threadIdx.x) >> 6;
    const int nw   = (gridDim.x * blockDim.x) >> 6;
    const int k    = lane & 31;
    const bool is_u = (lane < 32);

    float wp[4][4][7];
#pragma unroll
    for (int q = 0; q < 4; ++q)
#pragma unroll
        for (int t = 0; t < 4; ++t) {
            const int c = q * 256 + lane * 4 + t;
#pragma unroll
            for (int e = 0; e < 6; ++e) wp[q][t][e] = piece_w[c * 6 + e];
            wp[q][t][6] = color_w[c];
        }

    float wsp0 = mlp1_w[0 * 32 + k];
    float wsp1 = mlp1_w[1 * 32 + k];
    if (!is_u) { wsp0 = -wsp0; wsp1 = -wsp1; }
    const float bias1 = is_u ? mlp1_b[k] : 0.0f;
    float wc[6];
#pragma unroll
    for (int c = 0; c < 6; ++c)
        wc[c] = mlp1_w[((is_u ? 2 : 8) + c) * 32 + k];
    float pb[6];
#pragma unroll
    for (int e = 0; e < 6; ++e) pb[e] = piece_b[e];
    const float cb = color_b[0];

    for (int row = wid; row < NROWS; row += nw) {
        const float4* xr = (const float4*)(x + (size_t)row * DM);
        float4 xv[4];
#pragma unroll
        for (int q = 0; q < 4; ++q) xv[q] = xr[q * 64 + lane];

        float acc[7] = {0.f, 0.f, 0.f, 0.f, 0.f, 0.f, 0.f};
#pragma unroll
        for (int q = 0; q < 4; ++q) {
            const float xs[4] = {xv[q].x, xv[q].y, xv[q].z, xv[q].w};
#pragma unroll
            for (int t = 0; t < 4; ++t)
#pragma unroll
                for (int e = 0; e < 7; ++e)
                    acc[e] = fmaf(xs[t], wp[q][t][e], acc[e]);
        }

#pragma unroll
        for (int e = 0; e < 7; ++e) {
            acc[e] = dpp_add<0xB1>(acc[e]);
            acc[e] = dpp_add<0x4E>(acc[e]);
            acc[e] = dpp_add<0x124>(acc[e]);
            acc[e] = dpp_add<0x128>(acc[e]);
            acc[e] += __shfl_xor(acc[e], 16, 64);
            acc[e] += __shfl_xor(acc[e], 32, 64);
        }

        float p[6];
#pragma unroll
        for (int e = 0; e < 6; ++e) p[e] = acc[e] + pb[e];

        const int b = row / SEQ;
        const int n = row - b * SEQ;
        const float fx = (n < 64) ? (float)(n >> 3) : 0.0f;
        const float fy = (n < 64) ? (float)(n & 7) : 0.0f;

        float val = bias1;
        val = fmaf(fx, wsp0, val);
        val = fmaf(fy, wsp1, val);
#pragma unroll
        for (int c = 0; c < 6; ++c) val = fmaf(p[c], wc[c], val);

        ws[(size_t)b * WS_PER_B + (is_u ? 0 : VOFF) + n * P + k] = val;
        if (lane == 0) ws[(size_t)b * WS_PER_B + COFF + n] = acc[6] + cb;
    }
}

// ---------------- K2: no-LDS pair MLP, wave = (b, jt, i-quarter) ----------
// Block = 320 thr (5 waves, wave wv <-> jt=wv); grid = 512b x 4 i-quarters.
// v[jt]/cj in registers (one-time ws load); u[i]/col[i] per-iter global
// (L1/L2-hot broadcast segments). No LDS, no barrier -> ~15 waves/CU.
__global__ __launch_bounds__(320) void k2_pair(
    const float* __restrict__ ws,
    const float* __restrict__ mlp1_w,
    const float* __restrict__ mlp2_w, const float* __restrict__ mlp2_b,
    float* __restrict__ out)
{
    const int lane = threadIdx.x & 63;
    const int jt   = threadIdx.x >> 6;      // wave id = j-subtile 0..4
    const int blk  = blockIdx.x;
    const int b    = blk >> 2;
    const int iq   = blk & 3;

    const int e16 = lane & 15;
    const int kq  = lane >> 4;
    const int k0  = kq * 8;

    union { unsigned w[4]; short8 s; } A;   // A-frag = W2^T (rows 8..15 zero)
#pragma unroll
    for (int w = 0; w < 4; ++w) {
        const float lo = (e16 < 8) ? mlp2_w[(k0 + 2 * w) * 8 + e16] : 0.0f;
        const float hi = (e16 < 8) ? mlp2_w[(k0 + 2 * w + 1) * 8 + e16] : 0.0f;
        A.w[w] = cvt_pk_bf16(lo, hi);
    }
    v2f w14p[4];
#pragma unroll
    for (int w = 0; w < 4; ++w)
        w14p[w] = (v2f){mlp1_w[14 * 32 + k0 + 2 * w], mlp1_w[14 * 32 + k0 + 2 * w + 1]};
    float b2v[4];
#pragma unroll
    for (int q = 0; q < 4; ++q)
        b2v[q] = (kq < 2) ? mlp2_b[kq * 4 + q] : 0.0f;

    const float* wsb = ws + (size_t)b * WS_PER_B;

    // ---- one-time v/cj preload into registers (row 79 clamped to 78:
    //      defined data; its outputs are store-guarded)
    const int j  = jt * 16 + e16;
    const int jc = (j < SEQ) ? j : (SEQ - 1);
    const float4 va = *(const float4*)(wsb + VOFF + jc * P + k0);
    const float4 vb = *(const float4*)(wsb + VOFF + jc * P + k0 + 4);
    const float vv[8] = {va.x, va.y, va.z, va.w, vb.x, vb.y, vb.z, vb.w};
    const float cj = wsb[COFF + jc];

    const int i0 = iq * 20;
    const int i1 = (i0 + 20 < SEQ) ? i0 + 20 : SEQ;
    const size_t obb = (size_t)b * (8 * NPB);

    for (int i = i0; i < i1; ++i) {
        const float4 ua = *(const float4*)(wsb + i * P + k0);   // broadcast
        const float4 ub = *(const float4*)(wsb + i * P + k0 + 4);
        const float ci = wsb[COFF + i];
        const float uu[8] = {ua.x, ua.y, ua.z, ua.w, ub.x, ub.y, ub.z, ub.w};

        const float sw = (ci == cj) ? 1.0f : 0.0f;
        const v2f swp = {sw, sw};

        union { unsigned w[4]; short8 s; } B;
#pragma unroll
        for (int w = 0; w < 4; ++w) {
            v2f a = {uu[2 * w] + vv[2 * w], uu[2 * w + 1] + vv[2 * w + 1]};
            a = a + swp * w14p[w];
            const v2f h = gelu2(a);
            B.w[w] = cvt_pk_bf16(h.x, h.y);
        }

        f32x4 acc2 = {0.f, 0.f, 0.f, 0.f};
        acc2 = __builtin_amdgcn_mfma_f32_16x16x32_bf16(A.s, B.s, acc2, 0, 0, 0);

        // D: col = e16 (j), row = kq*4+q (e); rows 0..7 valid
        if (kq < 2 && j < SEQ) {
            float* o = out + obb + (size_t)(kq * 4) * NPB + (size_t)i * SEQ + j;
#pragma unroll
            for (int q = 0; q < 4; ++q)
                o[(size_t)q * NPB] = acc2[q] + b2v[q];
        }
    }
}

extern "C" void kernel_launch(void* const* d_in, const int* in_sizes, int n_in,
                              void* d_out, int out_size, void* d_ws, size_t ws_size,
                              hipStream_t stream) {
    const float* x       = (const float*)d_in[0];
    const float* piece_w = (const float*)d_in[1];
    const float* piece_b = (const float*)d_in[2];
    const float* color_w = (const float*)d_in[3];
    const float* color_b = (const float*)d_in[4];
    const float* mlp1_w  = (const float*)d_in[5];
    const float* mlp1_b  = (const float*)d_in[6];
    const float* mlp2_w  = (const float*)d_in[7];
    const float* mlp2_b  = (const float*)d_in[8];
    float* out = (float*)d_out;
    float* ws  = (float*)d_ws;   // 512*5776*4 = 11.83 MB

    hipLaunchKernelGGL(k1_embed, dim3(2048), dim3(256), 0, stream,
                       x, piece_w, piece_b, color_w, color_b, mlp1_w, mlp1_b, ws);
    hipLaunchKernelGGL(k2_pair, dim3(BATCHN * 4), dim3(320), 0, stream,
                       ws, mlp1_w, mlp2_w, mlp2_b, out);
}

// Round 19
// 68.877 us; speedup vs baseline: 1.2356x; 1.2356x over previous
//
#include <hip/hip_runtime.h>

#define SEQ 79
#define DM 1024
#define BATCHN 512
#define NPB (SEQ * SEQ)             // 6241
#define P 36                        // k-pitch in floats (16B-aligned, odd/32 banks)
#define NWAVES 4                    // 256-thread block

typedef float v2f   __attribute__((ext_vector_type(2)));
typedef float f32x4 __attribute__((ext_vector_type(4)));
typedef short short8 __attribute__((ext_vector_type(8)));

__device__ __forceinline__ unsigned cvt_pk_bf16(float lo, float hi) {
    unsigned r;
    asm("v_cvt_pk_bf16_f32 %0, %1, %2" : "=v"(r) : "v"(lo), "v"(hi));
    return r;
}

// DPP lane-shuffle add on the VALU pipe (not LDS): 0xB1=xor1, 0x4E=xor2,
// 0x124=row_ror:4, 0x128=row_ror:8 -> 16-lane sums after 4 steps.
template <int CTRL>
__device__ __forceinline__ float dpp_add(float v) {
    int t = __builtin_amdgcn_update_dpp(0, __builtin_bit_cast(int, v),
                                        CTRL, 0xf, 0xf, false);
    return v + __builtin_bit_cast(float, t);
}

__device__ __forceinline__ v2f gelu2(v2f a) {
    // gelu(a) = a - a / (exp2(c1*a + c2*a^3) + 1)
    const v2f C1 = {2.3022585093f, 2.3022585093f};
    const v2f C2 = {0.1029450750f, 0.1029450750f};
    v2f tt = a * (a * a * C2 + C1);
    v2f e;
    e.x = __builtin_amdgcn_exp2f(tt.x);
    e.y = __builtin_amdgcn_exp2f(tt.y);
    v2f ep = e + (v2f){1.f, 1.f};
    v2f r;
    r.x = __builtin_amdgcn_rcpf(ep.x);
    r.y = __builtin_amdgcn_rcpf(ep.y);
    return a - a * r;
}

// R17 base (passing, 69.8us; LDS-pipe fixed: conflicts 82K, VGPR 88).
// R18's 2-kernel split regressed (85us) -> fused stays. Residual diagnosis:
// ~45us stall at 8 waves/CU, dominated by phase-A dependent global loads
// (4 loads -> wait -> 330cy compute per row, 2 waves/SIMD).
// This round: 2-ROW LOAD BATCHING in phase A — issue 8 loads up front,
// compute row n while row n+4's loads fly. Straight-line dual body (R15
// pattern), clamped tail load + skipped body: no loop-carried regs.
__global__ __launch_bounds__(256) void fused_bias(
    const float* __restrict__ x,
    const float* __restrict__ piece_w, const float* __restrict__ piece_b,
    const float* __restrict__ color_w, const float* __restrict__ color_b,
    const float* __restrict__ mlp1_w,  const float* __restrict__ mlp1_b,
    const float* __restrict__ mlp2_w,  const float* __restrict__ mlp2_b,
    float* __restrict__ out)
{
    __shared__ float uL[80 * P];     // 11,520 B
    __shared__ float vL[80 * P];     // 11,520 B
    __shared__ float colL[80];

    const int tid  = threadIdx.x;
    const int lane = tid & 63;
    const int wv   = tid >> 6;       // wave id 0..3
    const int b    = blockIdx.x;
    const int k    = lane & 31;
    const bool is_u = (lane < 32);

    // ---- phase-A per-lane projection weights: c = q*256 + lane*4 + t
    float wp[4][4][7];
#pragma unroll
    for (int q = 0; q < 4; ++q)
#pragma unroll
        for (int t = 0; t < 4; ++t) {
            const int c = q * 256 + lane * 4 + t;
#pragma unroll
            for (int e = 0; e < 6; ++e) wp[q][t][e] = piece_w[c * 6 + e];
            wp[q][t][6] = color_w[c];
        }

    float wsp0 = mlp1_w[0 * 32 + k];
    float wsp1 = mlp1_w[1 * 32 + k];
    if (!is_u) { wsp0 = -wsp0; wsp1 = -wsp1; }
    const float bias1 = is_u ? mlp1_b[k] : 0.0f;
    float wc[6];
#pragma unroll
    for (int c = 0; c < 6; ++c)
        wc[c] = mlp1_w[((is_u ? 2 : 8) + c) * 32 + k];
    float pb[6];
#pragma unroll
    for (int e = 0; e < 6; ++e) pb[e] = piece_b[e];
    const float cb = color_b[0];

    // ---- phase-B lane constants
    const int e16 = lane & 15;          // j-in-subtile / W2 output index
    const int kq  = lane >> 4;          // k-quarter
    const int k0  = kq * 8;

    union { unsigned w[4]; short8 s; } A;   // A-frag = W2^T (rows 8..15 zero)
#pragma unroll
    for (int w = 0; w < 4; ++w) {
        const float lo = (e16 < 8) ? mlp2_w[(k0 + 2 * w) * 8 + e16] : 0.0f;
        const float hi = (e16 < 8) ? mlp2_w[(k0 + 2 * w + 1) * 8 + e16] : 0.0f;
        A.w[w] = cvt_pk_bf16(lo, hi);
    }
    v2f w14p[4];
#pragma unroll
    for (int w = 0; w < 4; ++w)
        w14p[w] = (v2f){mlp1_w[14 * 32 + k0 + 2 * w], mlp1_w[14 * 32 + k0 + 2 * w + 1]};
    float b2v[4];
#pragma unroll
    for (int q = 0; q < 4; ++q)
        b2v[q] = (kq < 2) ? mlp2_b[kq * 4 + q] : 0.0f;

    // defined padding for row 79 (j==79 reads feed MFMA col 15, store-guarded)
    if (wv == 0) {
        if (lane < P) vL[79 * P + lane] = 0.0f;
        if (lane == 0) colL[79] = 0.0f;
    }

    // ---------------- Phase A: 79 token rows -> LDS, 2 rows/iteration -------
    const float* xb = x + (size_t)b * SEQ * DM;
    for (int n = wv; n < SEQ; n += 2 * NWAVES) {
        const int n2  = n + NWAVES;
        const int n2c = (n2 < SEQ) ? n2 : n;   // clamped: loads always defined

        // issue all 8 loads up front (row n2's fly under row n's compute)
        const float4* xr0 = (const float4*)(xb + (size_t)n * DM);
        const float4* xr1 = (const float4*)(xb + (size_t)n2c * DM);
        float4 xv0[4], xv1[4];
#pragma unroll
        for (int q = 0; q < 4; ++q) xv0[q] = xr0[q * 64 + lane];
#pragma unroll
        for (int q = 0; q < 4; ++q) xv1[q] = xr1[q * 64 + lane];

        // ---- row n
        {
            float acc[7] = {0.f, 0.f, 0.f, 0.f, 0.f, 0.f, 0.f};
#pragma unroll
            for (int q = 0; q < 4; ++q) {
                const float xs[4] = {xv0[q].x, xv0[q].y, xv0[q].z, xv0[q].w};
#pragma unroll
                for (int t = 0; t < 4; ++t)
#pragma unroll
                    for (int e = 0; e < 7; ++e)
                        acc[e] = fmaf(xs[t], wp[q][t][e], acc[e]);
            }
#pragma unroll
            for (int e = 0; e < 7; ++e) {
                acc[e] = dpp_add<0xB1>(acc[e]);
                acc[e] = dpp_add<0x4E>(acc[e]);
                acc[e] = dpp_add<0x124>(acc[e]);
                acc[e] = dpp_add<0x128>(acc[e]);
                acc[e] += __shfl_xor(acc[e], 16, 64);
                acc[e] += __shfl_xor(acc[e], 32, 64);
            }
            float p[6];
#pragma unroll
            for (int e = 0; e < 6; ++e) p[e] = acc[e] + pb[e];
            const float fx = (n < 64) ? (float)(n >> 3) : 0.0f;
            const float fy = (n < 64) ? (float)(n & 7) : 0.0f;
            float val = bias1;
            val = fmaf(fx, wsp0, val);
            val = fmaf(fy, wsp1, val);
#pragma unroll
            for (int c = 0; c < 6; ++c) val = fmaf(p[c], wc[c], val);
            float* dst = is_u ? uL : vL;
            dst[n * P + k] = val;
            if (lane == 0) colL[n] = acc[6] + cb;
        }

        // ---- row n2 (skipped entirely on the tail; loads were clamped)
        if (n2 < SEQ) {
            float acc[7] = {0.f, 0.f, 0.f, 0.f, 0.f, 0.f, 0.f};
#pragma unroll
            for (int q = 0; q < 4; ++q) {
                const float xs[4] = {xv1[q].x, xv1[q].y, xv1[q].z, xv1[q].w};
#pragma unroll
                for (int t = 0; t < 4; ++t)
#pragma unroll
                    for (int e = 0; e < 7; ++e)
                        acc[e] = fmaf(xs[t], wp[q][t][e], acc[e]);
            }
#pragma unroll
            for (int e = 0; e < 7; ++e) {
                acc[e] = dpp_add<0xB1>(acc[e]);
                acc[e] = dpp_add<0x4E>(acc[e]);
                acc[e] = dpp_add<0x124>(acc[e]);
                acc[e] = dpp_add<0x128>(acc[e]);
                acc[e] += __shfl_xor(acc[e], 16, 64);
                acc[e] += __shfl_xor(acc[e], 32, 64);
            }
            float p[6];
#pragma unroll
            for (int e = 0; e < 6; ++e) p[e] = acc[e] + pb[e];
            const float fx = (n2 < 64) ? (float)(n2 >> 3) : 0.0f;
            const float fy = (n2 < 64) ? (float)(n2 & 7) : 0.0f;
            float val = bias1;
            val = fmaf(fx, wsp0, val);
            val = fmaf(fy, wsp1, val);
#pragma unroll
            for (int c = 0; c < 6; ++c) val = fmaf(p[c], wc[c], val);
            float* dst = is_u ? uL : vL;
            dst[n2 * P + k] = val;
            if (lane == 0) colL[n2] = acc[6] + cb;
        }
    }

    __syncthreads();

    // ---- Phase B prologue: hoist this lane's i-invariant v/col[j] into regs
    float vv[5][8];
    float cjv[5];
#pragma unroll
    for (int jt = 0; jt < 5; ++jt) {
        const int j = jt * 16 + e16;           // j==79 reads defined padding
        const float4 va = *(const float4*)(vL + j * P + k0);
        const float4 vb = *(const float4*)(vL + j * P + k0 + 4);
        vv[jt][0] = va.x; vv[jt][1] = va.y; vv[jt][2] = va.z; vv[jt][3] = va.w;
        vv[jt][4] = vb.x; vv[jt][5] = vb.y; vv[jt][6] = vb.z; vv[jt][7] = vb.w;
        cjv[jt] = colL[j];
    }

    // ------- Phase B: i-outer; inner 5 subtiles fully register-resident -----
    const size_t obb = (size_t)b * (8 * NPB);
    for (int i = wv; i < SEQ; i += NWAVES) {
        const float4 ua = *(const float4*)(uL + i * P + k0);   // per-i LDS
        const float4 ub = *(const float4*)(uL + i * P + k0 + 4);
        const float ci = colL[i];
        const float uu[8] = {ua.x, ua.y, ua.z, ua.w, ub.x, ub.y, ub.z, ub.w};

#pragma unroll
        for (int jt = 0; jt < 5; ++jt) {
            const int j = jt * 16 + e16;
            const float sw = (ci == cjv[jt]) ? 1.0f : 0.0f;
            const v2f swp = {sw, sw};

            union { unsigned w[4]; short8 s; } B;
#pragma unroll
            for (int w = 0; w < 4; ++w) {
                v2f a = {uu[2 * w] + vv[jt][2 * w], uu[2 * w + 1] + vv[jt][2 * w + 1]};
                a = a + swp * w14p[w];
                const v2f h = gelu2(a);
                B.w[w] = cvt_pk_bf16(h.x, h.y);
            }

            f32x4 acc2 = {0.f, 0.f, 0.f, 0.f};
            acc2 = __builtin_amdgcn_mfma_f32_16x16x32_bf16(A.s, B.s, acc2, 0, 0, 0);

            // D: col = e16 (j), row = kq*4+q (e); rows 0..7 valid
            if (kq < 2 && j < SEQ) {
                float* o = out + obb + (size_t)(kq * 4) * NPB + (size_t)i * SEQ + j;
#pragma unroll
                for (int q = 0; q < 4; ++q)
                    o[(size_t)q * NPB] = acc2[q] + b2v[q];
            }
        }
    }
}

extern "C" void kernel_launch(void* const* d_in, const int* in_sizes, int n_in,
                              void* d_out, int out_size, void* d_ws, size_t ws_size,
                              hipStream_t stream) {
    const float* x       = (const float*)d_in[0];
    const float* piece_w = (const float*)d_in[1];
    const float* piece_b = (const float*)d_in[2];
    const float* color_w = (const float*)d_in[3];
    const float* color_b = (const float*)d_in[4];
    const float* mlp1_w  = (const float*)d_in[5];
    const float* mlp1_b  = (const float*)d_in[6];
    const float* mlp2_w  = (const float*)d_in[7];
    const float* mlp2_b  = (const float*)d_in[8];
    float* out = (float*)d_out;

    hipLaunchKernelGGL(fused_bias, dim3(BATCHN), dim3(256), 0, stream,
                       x, piece_w, piece_b, color_w, color_b,
                       mlp1_w, mlp1_b, mlp2_w, mlp2_b, out);
}